// Round 1
// 135.535 us; speedup vs baseline: 1.0757x; 1.0757x over previous
//
#include <hip/hip_runtime.h>
#include <cstddef>

// Problem constants (bs=16, T=50, A=3, H=W=76, C=80, stride 8)
#define NB 16
#define NT 50
#define NA 3
#define NH 76
#define NW 76
#define NC 80
#define HWSZ (NH*NW)              // 5776
#define CPB 1024                  // cells per block (4 per thread)
#define NBLKX ((HWSZ + CPB - 1) / CPB)   // 6
#define NBULK (NBLKX * NB * NA)   // 288 bulk blocks
#define NTARG (NB * NT)           // 800
#define NSPB  ((NTARG + 3) / 4)   // 200 sparse blocks, one wave per target
// ws layout: [0..NBULK) bulk noobj partials;
//            [NBULK .. NBULK+6*NTARG) per-target channel values, ws[NBULK + k*NTARG + t]
#define WS_T NBULK

// scaled anchors = ANCHORS/8, scaled total = TOTAL/8
__constant__ float d_taw[9] = {1.25f,2.0f,4.125f,3.75f,7.75f,7.375f,14.5f,19.5f,46.625f};
__constant__ float d_tah[9] = {1.625f,3.75f,2.875f,7.625f,5.625f,14.875f,11.25f,24.75f,40.75f};
__constant__ float d_saw[3] = {1.25f,2.0f,4.125f};
__constant__ float d_sah[3] = {1.625f,3.75f,2.875f};

__device__ __forceinline__ float safelog(float p) {
    return p > 0.f ? logf(p) : -100.f;   // torch/jax BCE clamp
}
__device__ __forceinline__ float bce(float p, float t) {
    return -(t * safelog(p) + (1.f - t) * safelog(1.f - p));
}
__device__ __forceinline__ float sl1(float p, float t) {
    float d = fabsf(p - t);
    return d < 1.f ? 0.5f * d * d : d - 0.5f;
}
__device__ __forceinline__ float sigmoidf(float z) { return 1.f / (1.f + expf(-z)); }

struct TRec {
    bool valid, write;
    int ai, gi, gj, cls;
    float gx, gy, gw, gh;
};

__device__ __forceinline__ TRec decode(const float* __restrict__ tp) {
    TRec r;
    float t0 = tp[0], t1 = tp[1], t2 = tp[2], t3 = tp[3], t4 = tp[4];
    r.valid = (t0 + t1 + t2 + t3 + t4) != 0.f;
    r.gx = t1 * NW; r.gy = t2 * NH; r.gw = t3 * NW; r.gh = t4 * NH;
    r.gi = (int)r.gx; r.gj = (int)r.gy;       // truncation; gx,gy >= 0
    // best of 9 total anchors (centered -> inter = min(w)*min(h)); first-max wins
    float best = -1.f; int bn = 0;
    #pragma unroll
    for (int n = 0; n < 9; n++) {
        float inter = fminf(r.gw, d_taw[n]) * fminf(r.gh, d_tah[n]);
        float iou = inter / (r.gw * r.gh + d_taw[n] * d_tah[n] - inter + 1e-16f);
        if (iou > best) { best = iou; bn = n; }
    }
    r.ai = (bn < NA) ? bn : -1;
    r.write = r.valid && (r.ai >= 0);
    r.cls = (int)t0;
    return r;
}

// ---------- kernel 1: bulk per-cell work (blocks 0..287) + sparse per-target waves (288..487) ----------
__global__ __launch_bounds__(256) void k_main(const float* __restrict__ in,
                                              const float* __restrict__ tg,
                                              float* __restrict__ ws) {
    const int tid = threadIdx.x;
    const int wid = tid >> 6, lane = tid & 63;
    const int bid = blockIdx.x;

    if (bid >= NBULK) {
        // ======== sparse path: one wave per target, fully parallel ========
        const int t = (bid - NBULK) * 4 + wid;            // 0..799
        const int b = t / NT, tloc = t - b * NT;

        TRec r; r.valid = false; r.write = false;
        r.ai = -1; r.gi = -1; r.gj = -1; r.cls = 0;
        r.gx = r.gy = r.gw = r.gh = 0.f;
        float txl = 0.f, tyl = 0.f, twl = 0.f, thl = 0.f, scl = 0.f;
        if (lane < NT) {
            r = decode(tg + ((size_t)b * NT + lane) * 5);
            txl = r.gx - (float)r.gi; tyl = r.gy - (float)r.gj;
            int aic = r.ai < 0 ? 0 : r.ai;
            twl = logf(r.gw / d_saw[aic] + 1e-16f);
            thl = logf(r.gh / d_sah[aic] + 1e-16f);
            scl = 2.f - (r.gw / (float)NW) * (r.gh / (float)NH);
        }
        const int wflag = __shfl((int)r.write, tloc);      // is this wave's target matched?
        float v0 = 0.f, v1 = 0.f, v2 = 0.f, v3 = 0.f, v4 = 0.f, v5 = 0.f;
        if (wflag) {
            const int a  = __shfl(r.ai, tloc);
            const int gi = __shfl(r.gi, tloc);
            const int gj = __shfl(r.gj, tloc);
            bool match = r.write && (r.ai == a) && (r.gi == gi) && (r.gj == gj);
            unsigned long long mb = __ballot(match);       // lane tloc is set
            int tlast = 63 - __clzll((long long)mb);       // last scatter wins
            if (tloc == tlast) {                           // this wave owns the cell
                // tcls = OR over all matching targets
                unsigned long long m0 = 0ull; unsigned m1 = 0u;
                unsigned long long mm = mb;
                while (mm) {
                    int l = __ffsll(mm) - 1; mm &= mm - 1;
                    int c = __shfl(r.cls, l);
                    if (c < 64) m0 |= 1ull << c; else m1 |= 1u << (c - 64);
                }
                float tx = __shfl(txl, tlast), ty = __shfl(tyl, tlast);
                float tw = __shfl(twl, tlast), th = __shfl(thl, tlast);
                float sc = __shfl(scl, tlast);
                const size_t cb = ((size_t)b * 255 + (size_t)a * 85) * HWSZ
                                + (size_t)(gj * NW + gi);
                float z5 = (lane < 5) ? in[cb + (size_t)lane * HWSZ] : 0.f;
                float zx = __shfl(z5, 0), zy = __shfl(z5, 1), zww = __shfl(z5, 2),
                      zhh = __shfl(z5, 3), zcf = __shfl(z5, 4);
                float zca = in[cb + (size_t)(5 + lane) * HWSZ];       // classes 0..63
                float zcb = (lane < 16) ? in[cb + (size_t)(69 + lane) * HWSZ] : 0.f;
                float tca = ((m0 >> lane) & 1ull) ? 1.f : 0.f;
                float lcls = bce(sigmoidf(zca), tca);
                if (lane < 16) {
                    float tcb = ((m1 >> lane) & 1u) ? 1.f : 0.f;
                    lcls += bce(sigmoidf(zcb), tcb);
                }
                #pragma unroll
                for (int off = 32; off > 0; off >>= 1) lcls += __shfl_down(lcls, off);
                if (lane == 0) {
                    v0 = sc * bce(sigmoidf(zx), tx);
                    v1 = sc * bce(sigmoidf(zy), ty);
                    v2 = sc * sl1(zww, tw);
                    v3 = sc * sl1(zhh, th);
                    v4 = -safelog(sigmoidf(zcf));          // bce(conf,1)
                    v5 = lcls;
                }
            }
        }
        // every target slot must be written (ws is poisoned, not zeroed)
        if (lane == 0) {
            float* wt = ws + WS_T + t;
            wt[0 * NTARG] = v0; wt[1 * NTARG] = v1; wt[2 * NTARG] = v2;
            wt[3 * NTARG] = v3; wt[4 * NTARG] = v4; wt[5 * NTARG] = v5;
        }
        return;
    }

    // ======== bulk path: ignore test + noobj conf term, 4 cells/thread ========
    const int bx = bid % NBLKX;
    const int by = bid / NBLKX;          // 0..47
    const int b = by / NA;
    const int a = by % NA;
    const int base = bx * CPB;

    __shared__ __align__(16) float st[NT][8];  // [0..3]=x1,y1,x2,y2 [4]=area(+inf invalid)
    __shared__ int s_nm, s_moff[NT];
    __shared__ float red[4];

    if (tid == 0) s_nm = 0;
    __syncthreads();
    if (tid < NT) {
        TRec r = decode(tg + ((size_t)b * NT + tid) * 5);
        float x1 = r.gx - r.gw * 0.5f, y1 = r.gy - r.gh * 0.5f;
        float x2 = r.gx + r.gw * 0.5f, y2 = r.gy + r.gh * 0.5f;
        float* o = st[tid];
        o[0] = x1; o[1] = y1; o[2] = x2; o[3] = y2;
        o[4] = r.valid ? (x2 - x1) * (y2 - y1) : __builtin_inff();
        if (r.write && r.ai == a) {
            int off = r.gj * NW + r.gi - base;
            if (off >= 0 && off < CPB) {
                int slot = atomicAdd(&s_nm, 1);
                s_moff[slot] = off;              // masked cell in this block
            }
        }
    }
    __syncthreads();

    const float* ib = in + (size_t)(b * 255 + a * 85) * HWSZ;
    bool act[4]; int q[4];
    float zc[4], pxa[4], pxb[4], pya[4], pyb[4], pa[4];
    #pragma unroll
    for (int c = 0; c < 4; c++) {
        int p = base + c * 256 + tid;
        act[c] = p < HWSZ;
        q[c] = act[c] ? p : 0;
        float zx = ib[q[c]], zy = ib[HWSZ + q[c]], zw = ib[2 * HWSZ + q[c]],
              zh = ib[3 * HWSZ + q[c]];
        zc[c] = ib[4 * HWSZ + q[c]];
        int j = q[c] / NW, i = q[c] - j * NW;
        float x = sigmoidf(zx), y = sigmoidf(zy);
        float pbx = x + (float)i, pby = y + (float)j;
        float pbw = expf(zw) * d_saw[a], pbh = expf(zh) * d_sah[a];
        pxa[c] = pbx - pbw * 0.5f; pxb[c] = pbx + pbw * 0.5f;
        pya[c] = pby - pbh * 0.5f; pyb[c] = pby + pbh * 0.5f;
        pa[c] = (pxb[c] - pxa[c]) * (pyb[c] - pya[c]);
    }

    bool ig[4] = {false, false, false, false};
    for (int tb = 0; tb < NT; tb += 5) {
        float4 B[5]; float A_[5];
        #pragma unroll
        for (int u = 0; u < 5; u++) {
            B[u] = *(const float4*)&st[tb + u][0];
            A_[u] = st[tb + u][4];
        }
        #pragma unroll
        for (int u = 0; u < 5; u++) {
            #pragma unroll
            for (int c = 0; c < 4; c++) {
                float iw = fmaxf(fminf(B[u].z, pxb[c]) - fmaxf(B[u].x, pxa[c]), 0.f);
                float ih = fmaxf(fminf(B[u].w, pyb[c]) - fmaxf(B[u].y, pya[c]), 0.f);
                // iou >= 0.5  <=>  3*inter >= area_t + area_p  (denominator > 0)
                if (3.f * (iw * ih) >= A_[u] + pa[c]) ig[c] = true;
            }
        }
    }

    // noobj conf term; masked cells contribute nothing here
    const int nm = s_nm;                         // wave-uniform
    bool mm[4] = {false, false, false, false};
    for (int e = 0; e < nm; e++) {
        int mo = s_moff[e];
        #pragma unroll
        for (int c = 0; c < 4; c++) mm[c] |= (mo == c * 256 + tid);
    }
    float lc = 0.f;
    #pragma unroll
    for (int c = 0; c < 4; c++)
        if (act[c] && !mm[c] && !ig[c]) lc += 0.5f * (-safelog(1.f - sigmoidf(zc[c])));

    float s = lc;
    #pragma unroll
    for (int off = 32; off > 0; off >>= 1) s += __shfl_down(s, off);
    if (lane == 0) red[wid] = s;
    __syncthreads();
    if (tid == 0)
        ws[bid] = red[0] + red[1] + red[2] + red[3];
}

// ---------- kernel 2: reduce partials + n_obj count + finalize ----------
__global__ __launch_bounds__(256) void k_final(const float* __restrict__ ws,
                                               const float* __restrict__ tg,
                                               float* __restrict__ out) {
    const int tid = threadIdx.x;
    const int wid = tid >> 6, lane = tid & 63;
    float acc[8] = {0.f, 0.f, 0.f, 0.f, 0.f, 0.f, 0.f, 0.f};

    // per-target channel sums (coalesced: consecutive t across lanes)
    for (int t = tid; t < NTARG; t += 256) {
        #pragma unroll
        for (int k = 0; k < 6; k++) acc[k] += ws[WS_T + k * NTARG + t];
    }
    // bulk noobj partials
    for (int i = tid; i < NBULK; i += 256) acc[6] += ws[i];
    // n_obj = number of valid targets
    for (int t = tid; t < NTARG; t += 256) {
        const float* tp = tg + (size_t)t * 5;
        float s5 = tp[0] + tp[1] + tp[2] + tp[3] + tp[4];
        if (s5 != 0.f) acc[7] += 1.f;
    }

    #pragma unroll
    for (int k = 0; k < 8; k++) {
        #pragma unroll
        for (int off = 32; off > 0; off >>= 1) acc[k] += __shfl_down(acc[k], off);
    }
    __shared__ float red[4][8];
    if (lane == 0) {
        #pragma unroll
        for (int k = 0; k < 8; k++) red[wid][k] = acc[k];
    }
    __syncthreads();
    if (tid == 0) {
        float s[8];
        #pragma unroll
        for (int k = 0; k < 8; k++)
            s[k] = red[0][k] + red[1][k] + red[2][k] + red[3][k];
        float n = s[7];
        float lx = s[0] / n, ly = s[1] / n;
        float lw = s[2] / n, lh = s[3] / n;
        float lcf = (s[4] + s[6]) / n, lcl = s[5] / n;
        out[0] = 2.5f * (lx + ly) + 2.5f * (lw + lh) + lcf + lcl;
        out[1] = lx; out[2] = ly; out[3] = lw; out[4] = lh; out[5] = lcf; out[6] = lcl;
    }
}

extern "C" void kernel_launch(void* const* d_in, const int* in_sizes, int n_in,
                              void* d_out, int out_size, void* d_ws, size_t ws_size,
                              hipStream_t stream) {
    const float* input   = (const float*)d_in[0];   // [16,255,76,76] f32
    const float* targets = (const float*)d_in[1];   // [16,50,5] f32
    float* out = (float*)d_out;                     // 7 f32
    float* ws  = (float*)d_ws;

    k_main<<<dim3(NBULK + NSPB), 256, 0, stream>>>(input, targets, ws);
    k_final<<<1, 256, 0, stream>>>(ws, targets, out);
}

// Round 3
// 132.474 us; speedup vs baseline: 1.1006x; 1.0231x over previous
//
#include <hip/hip_runtime.h>
#include <cstddef>

// Problem constants (bs=16, T=50, A=3, H=W=76, C=80, stride 8)
#define NB 16
#define NT 50
#define NA 3
#define NH 76
#define NW 76
#define NC 80
#define HWSZ (NH*NW)              // 5776
#define CPB 1156                  // cells per block (5 per thread; 5*1156=5780 >= 5776)
#define NBLKX 5                   // ceil(5776/1156)
#define NBULK (NBLKX * NB * NA)   // 240 bulk blocks -> <=1 heavy block per CU
#define NTARG (NB * NT)           // 800
#define NSPB  ((NTARG + 3) / 4)   // 200 sparse blocks, one wave per target
// ws layout: [0..NBULK) bulk noobj partials;
//            [NBULK .. NBULK+7*NSPB) sparse per-block channels, ws[NBULK + k*NSPB + blk]
//            k = 0..5 loss channels, k = 6 valid-target count
#define WS_SP NBULK

// scaled anchors = ANCHORS/8, scaled total = TOTAL/8
__constant__ float d_taw[9] = {1.25f,2.0f,4.125f,3.75f,7.75f,7.375f,14.5f,19.5f,46.625f};
__constant__ float d_tah[9] = {1.625f,3.75f,2.875f,7.625f,5.625f,14.875f,11.25f,24.75f,40.75f};
__constant__ float d_saw[3] = {1.25f,2.0f,4.125f};
__constant__ float d_sah[3] = {1.625f,3.75f,2.875f};

__device__ __forceinline__ float safelog(float p) {
    return p > 0.f ? logf(p) : -100.f;   // torch/jax BCE clamp
}
__device__ __forceinline__ float bce(float p, float t) {
    return -(t * safelog(p) + (1.f - t) * safelog(1.f - p));
}
__device__ __forceinline__ float sl1(float p, float t) {
    float d = fabsf(p - t);
    return d < 1.f ? 0.5f * d * d : d - 0.5f;
}
__device__ __forceinline__ float sigmoidf(float z) { return 1.f / (1.f + expf(-z)); }

struct TRec {
    bool valid, write;
    int ai, gi, gj, cls;
    float gx, gy, gw, gh;
};

__device__ __forceinline__ TRec decode(const float* __restrict__ tp) {
    TRec r;
    float t0 = tp[0], t1 = tp[1], t2 = tp[2], t3 = tp[3], t4 = tp[4];
    r.valid = (t0 + t1 + t2 + t3 + t4) != 0.f;
    r.gx = t1 * NW; r.gy = t2 * NH; r.gw = t3 * NW; r.gh = t4 * NH;
    r.gi = (int)r.gx; r.gj = (int)r.gy;       // truncation; gx,gy >= 0
    // best of 9 total anchors (centered -> inter = min(w)*min(h)); first-max wins
    float best = -1.f; int bn = 0;
    #pragma unroll
    for (int n = 0; n < 9; n++) {
        float inter = fminf(r.gw, d_taw[n]) * fminf(r.gh, d_tah[n]);
        float iou = inter / (r.gw * r.gh + d_taw[n] * d_tah[n] - inter + 1e-16f);
        if (iou > best) { best = iou; bn = n; }
    }
    r.ai = (bn < NA) ? bn : -1;
    r.write = r.valid && (r.ai >= 0);
    r.cls = (int)t0;
    return r;
}

// ---------- kernel 1: bulk per-cell work (blocks 0..239) + sparse per-target waves (240..439) ----------
__global__ __launch_bounds__(256) void k_main(const float* __restrict__ in,
                                              const float* __restrict__ tg,
                                              float* __restrict__ ws) {
    const int tid = threadIdx.x;
    const int wid = tid >> 6, lane = tid & 63;
    const int bid = blockIdx.x;

    if (bid >= NBULK) {
        // ======== sparse path: one wave per target, fully parallel ========
        const int sblk = bid - NBULK;                     // 0..199
        const int t = sblk * 4 + wid;                     // 0..799
        const int b = t / NT, tloc = t - b * NT;

        __shared__ float sred[4][8];

        TRec r; r.valid = false; r.write = false;
        r.ai = -1; r.gi = -1; r.gj = -1; r.cls = 0;
        r.gx = r.gy = r.gw = r.gh = 0.f;
        float txl = 0.f, tyl = 0.f, twl = 0.f, thl = 0.f, scl = 0.f;
        if (lane < NT) {
            r = decode(tg + ((size_t)b * NT + lane) * 5);
            txl = r.gx - (float)r.gi; tyl = r.gy - (float)r.gj;
            int aic = r.ai < 0 ? 0 : r.ai;
            twl = logf(r.gw / d_saw[aic] + 1e-16f);
            thl = logf(r.gh / d_sah[aic] + 1e-16f);
            scl = 2.f - (r.gw / (float)NW) * (r.gh / (float)NH);
        }
        const int vld   = __shfl((int)r.valid, tloc);      // this wave's target valid?
        const int wflag = __shfl((int)r.write, tloc);      // matched to this head?
        float v0 = 0.f, v1 = 0.f, v2 = 0.f, v3 = 0.f, v4 = 0.f, v5 = 0.f;
        if (wflag) {
            const int a  = __shfl(r.ai, tloc);
            const int gi = __shfl(r.gi, tloc);
            const int gj = __shfl(r.gj, tloc);
            bool match = r.write && (r.ai == a) && (r.gi == gi) && (r.gj == gj);
            unsigned long long mb = __ballot(match);       // lane tloc is set
            int tlast = 63 - __clzll((long long)mb);       // last scatter wins
            if (tloc == tlast) {                           // this wave owns the cell
                // tcls = OR over all matching targets
                unsigned long long m0 = 0ull; unsigned m1 = 0u;
                unsigned long long mm = mb;
                while (mm) {
                    int l = __ffsll(mm) - 1; mm &= mm - 1;
                    int c = __shfl(r.cls, l);
                    if (c < 64) m0 |= 1ull << c; else m1 |= 1u << (c - 64);
                }
                float tx = __shfl(txl, tlast), ty = __shfl(tyl, tlast);
                float tw = __shfl(twl, tlast), th = __shfl(thl, tlast);
                float sc = __shfl(scl, tlast);
                const size_t cb = ((size_t)b * 255 + (size_t)a * 85) * HWSZ
                                + (size_t)(gj * NW + gi);
                float z5 = (lane < 5) ? in[cb + (size_t)lane * HWSZ] : 0.f;
                float zx = __shfl(z5, 0), zy = __shfl(z5, 1), zww = __shfl(z5, 2),
                      zhh = __shfl(z5, 3), zcf = __shfl(z5, 4);
                float zca = in[cb + (size_t)(5 + lane) * HWSZ];       // classes 0..63
                float zcb = (lane < 16) ? in[cb + (size_t)(69 + lane) * HWSZ] : 0.f;
                float tca = ((m0 >> lane) & 1ull) ? 1.f : 0.f;
                float lcls = bce(sigmoidf(zca), tca);
                if (lane < 16) {
                    float tcb = ((m1 >> lane) & 1u) ? 1.f : 0.f;
                    lcls += bce(sigmoidf(zcb), tcb);
                }
                #pragma unroll
                for (int off = 32; off > 0; off >>= 1) lcls += __shfl_down(lcls, off);
                if (lane == 0) {
                    v0 = sc * bce(sigmoidf(zx), tx);
                    v1 = sc * bce(sigmoidf(zy), ty);
                    v2 = sc * sl1(zww, tw);
                    v3 = sc * sl1(zhh, th);
                    v4 = -safelog(sigmoidf(zcf));          // bce(conf,1)
                    v5 = lcls;
                }
            }
        }
        if (lane == 0) {
            sred[wid][0] = v0; sred[wid][1] = v1; sred[wid][2] = v2;
            sred[wid][3] = v3; sred[wid][4] = v4; sred[wid][5] = v5;
            sred[wid][6] = (float)vld;
        }
        __syncthreads();
        if (tid < 7) {
            float s = sred[0][tid] + sred[1][tid] + sred[2][tid] + sred[3][tid];
            ws[WS_SP + tid * NSPB + sblk] = s;
        }
        return;
    }

    // ======== bulk path: ignore test + noobj conf term, 5 cells/thread ========
    const int bx = bid % NBLKX;
    const int by = bid / NBLKX;          // 0..47
    const int b = by / NA;
    const int a = by % NA;
    const int base = bx * CPB;

    __shared__ __align__(16) float st[NT][8];  // [0..3]=x1,y1,x2,y2 [4]=area(+inf invalid)
    __shared__ int s_nm, s_moff[NT];
    __shared__ float red[4];

    if (tid == 0) s_nm = 0;
    __syncthreads();
    if (tid < NT) {
        TRec r = decode(tg + ((size_t)b * NT + tid) * 5);
        float x1 = r.gx - r.gw * 0.5f, y1 = r.gy - r.gh * 0.5f;
        float x2 = r.gx + r.gw * 0.5f, y2 = r.gy + r.gh * 0.5f;
        float* o = st[tid];
        o[0] = x1; o[1] = y1; o[2] = x2; o[3] = y2;
        o[4] = r.valid ? (x2 - x1) * (y2 - y1) : __builtin_inff();
        if (r.write && r.ai == a) {
            int off = r.gj * NW + r.gi - base;
            if (off >= 0 && off < CPB) {
                int slot = atomicAdd(&s_nm, 1);
                s_moff[slot] = off;              // masked cell in this block
            }
        }
    }
    __syncthreads();

    const float* ib = in + (size_t)(b * 255 + a * 85) * HWSZ;
    bool act[5]; int q[5];
    float zc[5], pxa[5], pxb[5], pya[5], pyb[5], pa[5];
    #pragma unroll
    for (int c = 0; c < 5; c++) {
        int off = c * 256 + tid;
        int p = base + off;
        act[c] = (off < CPB) && (p < HWSZ);
        q[c] = act[c] ? p : 0;
        float zx = ib[q[c]], zy = ib[HWSZ + q[c]], zw = ib[2 * HWSZ + q[c]],
              zh = ib[3 * HWSZ + q[c]];
        zc[c] = ib[4 * HWSZ + q[c]];
        int j = q[c] / NW, i = q[c] - j * NW;
        float x = sigmoidf(zx), y = sigmoidf(zy);
        float pbx = x + (float)i, pby = y + (float)j;
        float pbw = expf(zw) * d_saw[a], pbh = expf(zh) * d_sah[a];
        pxa[c] = pbx - pbw * 0.5f; pxb[c] = pbx + pbw * 0.5f;
        pya[c] = pby - pbh * 0.5f; pyb[c] = pby + pbh * 0.5f;
        pa[c] = (pxb[c] - pxa[c]) * (pyb[c] - pya[c]);
    }

    bool ig[5] = {false, false, false, false, false};
    for (int tb = 0; tb < NT; tb += 5) {
        float4 B[5]; float A_[5];
        #pragma unroll
        for (int u = 0; u < 5; u++) {
            B[u] = *(const float4*)&st[tb + u][0];
            A_[u] = st[tb + u][4];
        }
        #pragma unroll
        for (int u = 0; u < 5; u++) {
            #pragma unroll
            for (int c = 0; c < 5; c++) {
                float iw = fmaxf(fminf(B[u].z, pxb[c]) - fmaxf(B[u].x, pxa[c]), 0.f);
                float ih = fmaxf(fminf(B[u].w, pyb[c]) - fmaxf(B[u].y, pya[c]), 0.f);
                // iou >= 0.5  <=>  3*inter >= area_t + area_p  (denominator > 0)
                if (3.f * (iw * ih) >= A_[u] + pa[c]) ig[c] = true;
            }
        }
    }

    // noobj conf term; masked cells contribute nothing here
    const int nm = s_nm;                         // wave-uniform
    bool mm[5] = {false, false, false, false, false};
    for (int e = 0; e < nm; e++) {
        int mo = s_moff[e];
        #pragma unroll
        for (int c = 0; c < 5; c++) mm[c] |= (mo == c * 256 + tid);
    }
    float lc = 0.f;
    #pragma unroll
    for (int c = 0; c < 5; c++)
        if (act[c] && !mm[c] && !ig[c]) lc += 0.5f * (-safelog(1.f - sigmoidf(zc[c])));

    float s = lc;
    #pragma unroll
    for (int off = 32; off > 0; off >>= 1) s += __shfl_down(s, off);
    if (lane == 0) red[wid] = s;
    __syncthreads();
    if (tid == 0)
        ws[bid] = red[0] + red[1] + red[2] + red[3];
}

// ---------- kernel 2: compact reduce + finalize ----------
__global__ __launch_bounds__(256) void k_final(const float* __restrict__ ws,
                                               float* __restrict__ out) {
    const int tid = threadIdx.x;
    const int wid = tid >> 6, lane = tid & 63;
    float acc[8] = {0.f, 0.f, 0.f, 0.f, 0.f, 0.f, 0.f, 0.f};

    // sparse per-block channels (planar, coalesced): acc[0..5]=losses, acc[6]=n_obj
    if (tid < NSPB) {
        #pragma unroll
        for (int k = 0; k < 7; k++) acc[k] = ws[WS_SP + k * NSPB + tid];
    }
    // bulk noobj partials
    if (tid < NBULK) acc[7] = ws[tid];

    #pragma unroll
    for (int k = 0; k < 8; k++) {
        #pragma unroll
        for (int off = 32; off > 0; off >>= 1) acc[k] += __shfl_down(acc[k], off);
    }
    __shared__ float red[4][8];
    if (lane == 0) {
        #pragma unroll
        for (int k = 0; k < 8; k++) red[wid][k] = acc[k];
    }
    __syncthreads();
    if (tid == 0) {
        float s[8];
        #pragma unroll
        for (int k = 0; k < 8; k++)
            s[k] = red[0][k] + red[1][k] + red[2][k] + red[3][k];
        float n = s[6];
        float lx = s[0] / n, ly = s[1] / n;
        float lw = s[2] / n, lh = s[3] / n;
        float lcf = (s[4] + s[7]) / n, lcl = s[5] / n;
        out[0] = 2.5f * (lx + ly) + 2.5f * (lw + lh) + lcf + lcl;
        out[1] = lx; out[2] = ly; out[3] = lw; out[4] = lh; out[5] = lcf; out[6] = lcl;
    }
}

extern "C" void kernel_launch(void* const* d_in, const int* in_sizes, int n_in,
                              void* d_out, int out_size, void* d_ws, size_t ws_size,
                              hipStream_t stream) {
    const float* input   = (const float*)d_in[0];   // [16,255,76,76] f32
    const float* targets = (const float*)d_in[1];   // [16,50,5] f32
    float* out = (float*)d_out;                     // 7 f32
    float* ws  = (float*)d_ws;

    k_main<<<dim3(NBULK + NSPB), 256, 0, stream>>>(input, targets, ws);
    k_final<<<1, 256, 0, stream>>>(ws, out);
}